// Round 4
// baseline (274.522 us; speedup 1.0000x reference)
//
#include <hip/hip_runtime.h>

// SlotAttention on MI355X (gfx950).
// R3: gemm_kv register-level software pipeline — fragment double-buffer one
// K-tile ahead (FA/FB, statically named), so ds_reads of tile t+1 interleave
// with MFMAs of tile t. One counted vmcnt(4) + raw s_barrier per K-tile.

#define TS 64
#define TD 4096
#define BATCH 8
#define HC 1024
#define NHEAD 16
#define MD (TD*BATCH)   // 32768
#define MS (TS*BATCH)   // 512
#define NCHUNK 8
#define CHTOK (TD/NCHUNK) // 512

#define KTILES 32       // K=1024 / BK=32

typedef __attribute__((ext_vector_type(8))) __bf16 bf16x8;
typedef __attribute__((ext_vector_type(4))) float f32x4;
typedef __attribute__((ext_vector_type(4))) unsigned short u16x4;
typedef __attribute__((ext_vector_type(8))) unsigned short u16x8;

__device__ __forceinline__ unsigned short f2bf(float x){
  union { float f; unsigned u; } v; v.f = x;
  unsigned r = v.u + 0x7FFFu + ((v.u >> 16) & 1u);
  return (unsigned short)(r >> 16);
}

__device__ __forceinline__ void gll16(const void* g, void* l){
  __builtin_amdgcn_global_load_lds((__attribute__((address_space(1))) void*)g,
                                   (__attribute__((address_space(3))) void*)l, 16, 0, 0);
}

__global__ void cvt_bf16(const float* __restrict__ in, unsigned short* __restrict__ out, int n4){
  int i = blockIdx.x * blockDim.x + threadIdx.x;
  if (i >= n4) return;
  f32x4 f = ((const f32x4*)in)[i];
  u16x4 o;
  o[0] = f2bf(f[0]); o[1] = f2bf(f[1]); o[2] = f2bf(f[2]); o[3] = f2bf(f[3]);
  ((u16x4*)out)[i] = o;
}

// ---------------------------------------------------------------------------
// Fused K|V GEMM: C[32768 x 2048] = A @ [Wk;Wv]^T + [bk;bv], bf16 in/out.
// 256x256 tile, BK=32, 8 waves (2Mx4N), per-wave output 128x64.
// LDS: 4-slot ring (128 KiB), staging 3 tiles ahead (4 loads/wave/tile).
// Register pipeline: during tile t -> stage(t+3), read frags(t+1) into the
// idle fragment set, MFMA on the ready set. ds_reads have no same-tile
// consumer, so they interleave with the MFMA cluster.
// Boundary B_{t+1} (end of tile t): vmcnt(4) ensures slot t+2 retired for
// ALL waves (barrier) before anyone reads its frags in tile t+1; stage into
// slot (t+3)&3 is WAR-safe because slot t-1's reads completed at MFMA issue
// during tile t-1, before the previous barrier.
// ---------------------------------------------------------------------------
__global__ __launch_bounds__(512, 2) void gemm_kv(
    const unsigned short* __restrict__ A,     // [32768][1024]
    const unsigned short* __restrict__ W,     // [2048][1024] = Wk rows then Wv rows
    const float* __restrict__ bk,
    const float* __restrict__ bv,
    unsigned short* __restrict__ Kout,
    unsigned short* __restrict__ Vout)
{
  __shared__ unsigned short As[4][256*32];
  __shared__ unsigned short Bs[4][256*32];

  const int nwg = gridDim.x;                 // 1024 (multiple of 8)
  const int cpx = nwg >> 3;
  const int orig = blockIdx.x;
  const int wg = (orig & 7) * cpx + (orig >> 3);   // bijective XCD swizzle
  const int mt = wg >> 3, nt = wg & 7;
  const int tid = threadIdx.x;
  const int lane = tid & 63, w = tid >> 6;   // 8 waves
  const int l15 = lane & 15, lg = lane >> 4;
  const int wm = w >> 2, wn = w & 3;

  // ---- staging addressing (pre-swizzled global source, linear LDS dest) ----
  const int lr = lane >> 2;
  const int schunk = (((lane & 3) ^ ((lane >> 3) & 3)) << 4);
  const char* pa[2]; const char* pb[2]; unsigned ldso[2];
  #pragma unroll
  for (int j = 0; j < 2; ++j){
    int grow = j*128 + w*16 + lr;
    pa[j] = (const char*)A + (size_t)(mt*256 + grow)*2048 + schunk;
    pb[j] = (const char*)W + (size_t)(nt*256 + grow)*2048 + schunk;
    ldso[j] = (unsigned)(j*8192 + w*1024);   // wave-uniform; HW adds lane*16
  }

  #define STAGE_AB(t) { \
    char* da = (char*)&As[(t)&3][0]; \
    char* db = (char*)&Bs[(t)&3][0]; \
    gll16(pa[0] + (size_t)(t)*64, da + ldso[0]); \
    gll16(pa[1] + (size_t)(t)*64, da + ldso[1]); \
    gll16(pb[0] + (size_t)(t)*64, db + ldso[0]); \
    gll16(pb[1] + (size_t)(t)*64, db + ldso[1]); }

  // ---- fragment read offsets (swizzle: chunk = lg ^ ((row>>1)&3)) ----
  const unsigned cswz = ((unsigned)(lg ^ ((l15 >> 1) & 3))) << 4;
  const unsigned aoff = (unsigned)(wm*128 + l15)*64 + cswz;   // + mf*1024
  const unsigned boff = (unsigned)(wn*64  + l15)*64 + cswz;   // + nf*1024

  struct FragSet { bf16x8 a[8]; bf16x8 b[4]; };
  FragSet FA, FB;

  #define READ_FRAGS(F, slot) { \
    const char* as_ = (const char*)&As[(slot)][0]; \
    const char* bs_ = (const char*)&Bs[(slot)][0]; \
    _Pragma("unroll") \
    for (int mf = 0; mf < 8; ++mf) F.a[mf] = *(const bf16x8*)(as_ + aoff + mf*1024u); \
    _Pragma("unroll") \
    for (int nf = 0; nf < 4; ++nf) F.b[nf] = *(const bf16x8*)(bs_ + boff + nf*1024u); }

  #define DO_MFMA(F) { \
    __builtin_amdgcn_s_setprio(1); \
    _Pragma("unroll") \
    for (int mf = 0; mf < 8; ++mf) \
      _Pragma("unroll") \
      for (int nf = 0; nf < 4; ++nf) \
        acc[mf][nf] = __builtin_amdgcn_mfma_f32_16x16x32_bf16(F.a[mf], F.b[nf], acc[mf][nf], 0, 0, 0); \
    __builtin_amdgcn_s_setprio(0); }

  // B_{t+1}: end-of-tile-t boundary. vmcnt(4): slot t+2 retired, t+3 in flight.
  #define BOUNDARY(t) { \
    __builtin_amdgcn_sched_barrier(0); \
    if ((t) < KTILES - 3)       { asm volatile("s_waitcnt vmcnt(4)" ::: "memory"); } \
    else if ((t) == KTILES - 3) { asm volatile("s_waitcnt vmcnt(0)" ::: "memory"); } \
    __builtin_amdgcn_s_barrier(); \
    __builtin_amdgcn_sched_barrier(0); }

  const f32x4 fz = {0.f, 0.f, 0.f, 0.f};
  f32x4 acc[8][4];
  #pragma unroll
  for (int m = 0; m < 8; ++m)
    #pragma unroll
    for (int n = 0; n < 4; ++n) acc[m][n] = fz;

  // ---- prologue: stage 0,1,2; wait slots 0,1 retired (slot 2 in flight);
  // read frags(0).
  STAGE_AB(0) STAGE_AB(1) STAGE_AB(2)
  asm volatile("s_waitcnt vmcnt(4)" ::: "memory");
  __builtin_amdgcn_s_barrier();
  __builtin_amdgcn_sched_barrier(0);
  READ_FRAGS(FA, 0)

  #pragma unroll 1
  for (int tp = 0; tp < KTILES/2; ++tp){
    const int t = tp*2;
    // ---- even tile t: MFMA(FA) while FB <- frags(t+1)
    if (t + 3 < KTILES) STAGE_AB(t + 3)
    READ_FRAGS(FB, (t+1) & 3)            // t+1 <= 31 always
    DO_MFMA(FA)
    BOUNDARY(t)
    // ---- odd tile t+1: MFMA(FB) while FA <- frags(t+2)
    if (t + 4 < KTILES) STAGE_AB(t + 4)
    if (t + 2 < KTILES) READ_FRAGS(FA, (t+2) & 3)
    DO_MFMA(FB)
    BOUNDARY(t + 1)
  }

  // ---- epilogue: bias + bf16 store (block's 256 cols uniformly K or V)
  const int ccol = (nt & 3)*256 + wn*64;
  unsigned short* Cb = (nt < 4) ? Kout : Vout;
  const float* bias = (nt < 4) ? bk : bv;
  float bvv[4];
  #pragma unroll
  for (int nf = 0; nf < 4; ++nf) bvv[nf] = bias[ccol + nf*16 + l15];
  #pragma unroll
  for (int mf = 0; mf < 8; ++mf){
    #pragma unroll
    for (int r = 0; r < 4; ++r){
      size_t row = (size_t)(mt*256 + wm*128 + mf*16 + lg*4 + r);
      unsigned short* cp = Cb + row*1024 + ccol;
      #pragma unroll
      for (int nf = 0; nf < 4; ++nf)
        cp[nf*16 + l15] = f2bf(acc[mf][nf][r] + bvv[nf]);
    }
  }
  #undef STAGE_AB
  #undef READ_FRAGS
  #undef DO_MFMA
  #undef BOUNDARY
}

// ---------------------------------------------------------------------------
// 128^2 GEMM kept for Q (M=512): verified in R0.
// ---------------------------------------------------------------------------
__global__ __launch_bounds__(256) void gemm128(
    const unsigned short* __restrict__ A,
    const unsigned short* __restrict__ W,
    const float* __restrict__ bias,
    unsigned short* __restrict__ C)
{
  __shared__ unsigned short As[128*64];
  __shared__ unsigned short Bs[128*64];
  const int nwg = gridDim.x;
  const int cpx = nwg >> 3;
  const int orig = blockIdx.x;
  const int wg = (orig & 7) * cpx + (orig >> 3);
  const int mt = wg >> 3, nt = wg & 7;
  const int tid = threadIdx.x;
  const int lane = tid & 63, w = tid >> 6;
  const int l15 = lane & 15, lg = lane >> 4;
  const int wr = w >> 1, wc = w & 1;

  const int lrow = lane >> 3;
  const int lch  = (lane & 7) << 4;
  const char* pA[4]; const char* pB[4]; unsigned ldsoff[4];
  #pragma unroll
  for (int j = 0; j < 4; ++j){
    int row = w*32 + j*8 + lrow;
    int sw  = lch ^ ((row & 7) << 4);
    pA[j] = (const char*)A + (size_t)(mt*128 + row) * 2048 + sw;
    pB[j] = (const char*)W + (size_t)(nt*128 + row) * 2048 + sw;
    ldsoff[j] = (unsigned)(w*32 + j*8) * 128;
  }

  const f32x4 fz = {0.f, 0.f, 0.f, 0.f};
  f32x4 acc[4][4];
  #pragma unroll
  for (int m = 0; m < 4; ++m)
    #pragma unroll
    for (int n = 0; n < 4; ++n) acc[m][n] = fz;

  for (int kt = 0; kt < 16; ++kt){
    __syncthreads();
    #pragma unroll
    for (int j = 0; j < 4; ++j){
      gll16(pA[j] + (size_t)kt*128, (char*)As + ldsoff[j]);
      gll16(pB[j] + (size_t)kt*128, (char*)Bs + ldsoff[j]);
    }
    __syncthreads();
    #pragma unroll
    for (int kk = 0; kk < 2; ++kk){
      bf16x8 af[4], bfr[4];
      #pragma unroll
      for (int m = 0; m < 4; ++m){
        int row = wr*64 + m*16 + l15;
        af[m] = *(const bf16x8*)((const char*)As + row*128 + ((lg*16 + kk*64) ^ ((row & 7) << 4)));
      }
      #pragma unroll
      for (int n = 0; n < 4; ++n){
        int row = wc*64 + n*16 + l15;
        bfr[n] = *(const bf16x8*)((const char*)Bs + row*128 + ((lg*16 + kk*64) ^ ((row & 7) << 4)));
      }
      #pragma unroll
      for (int m = 0; m < 4; ++m)
        #pragma unroll
        for (int n = 0; n < 4; ++n)
          acc[m][n] = __builtin_amdgcn_mfma_f32_16x16x32_bf16(af[m], bfr[n], acc[m][n], 0, 0, 0);
    }
  }

  const int ccol0 = nt*128 + wc*64;
  float bv[4];
  #pragma unroll
  for (int n = 0; n < 4; ++n) bv[n] = bias[ccol0 + n*16 + l15];
  #pragma unroll
  for (int m = 0; m < 4; ++m){
    #pragma unroll
    for (int r = 0; r < 4; ++r){
      size_t row = (size_t)(mt*128 + wr*64 + m*16 + lg*4 + r);
      unsigned short* cp = C + row*1024 + ccol0;
      #pragma unroll
      for (int n = 0; n < 4; ++n)
        cp[n*16 + l15] = f2bf(acc[m][n][r] + bv[n]);
    }
  }
}

// one block per (b*16+h, chunk). 256 threads = 4 waves; wave w owns slots [16w,16w+16).
__global__ __launch_bounds__(256) void attn_kernel(
    const unsigned short* __restrict__ Q,
    const unsigned short* __restrict__ K,
    const unsigned short* __restrict__ V,
    float* __restrict__ P)
{
  __shared__ unsigned short Qs[64*64];
  __shared__ unsigned short Ks[64*64];
  __shared__ unsigned short Vt[80*64];
  __shared__ unsigned short Al[64*64];
  __shared__ float red[256];

  const int bh = blockIdx.x;
  const int chunk = blockIdx.y;
  const int bb = bh >> 4, h = bh & 15;
  const int tid = threadIdx.x;
  const int lane = tid & 63, w = tid >> 6;
  const int l15 = lane & 15, lg = lane >> 4;
  const int lrow = lane >> 3, lch = (lane & 7) << 4;

  for (int i = tid; i < 16*64; i += 256){
    int r = i >> 6;
    Vt[(64 + r)*64 + (i & 63)] = (r == 0) ? (unsigned short)0x3F80 : (unsigned short)0;
  }

  #pragma unroll
  for (int j = 0; j < 2; ++j){
    int row = w*16 + j*8 + lrow;
    int sw = lch ^ ((row & 7) << 4);
    const char* g = (const char*)Q + (size_t)(row*BATCH + bb)*2048 + h*128 + sw;
    gll16(g, (char*)Qs + (w*16 + j*8)*128);
  }

  const f32x4 fz = {0.f, 0.f, 0.f, 0.f};
  f32x4 acc[5];
  #pragma unroll
  for (int nb = 0; nb < 5; ++nb) acc[nb] = fz;

  const int vtok = tid >> 2;
  const int vcg  = tid & 3;
  const int t0 = chunk * CHTOK;

  for (int tt = 0; tt < CHTOK/64; ++tt){
    const int tb = t0 + tt*64;
    #pragma unroll
    for (int j = 0; j < 2; ++j){
      int row = w*16 + j*8 + lrow;
      int sw = lch ^ ((row & 7) << 4);
      const char* g = (const char*)K + (size_t)((size_t)(tb + row)*BATCH + bb)*2048 + h*128 + sw;
      gll16(g, (char*)Ks + (w*16 + j*8)*128);
    }
    const char* vg = (const char*)V + (size_t)((size_t)(tb + vtok)*BATCH + bb)*2048 + h*128 + vcg*32;
    u16x8 v0 = *(const u16x8*)vg;
    u16x8 v1 = *(const u16x8*)(vg + 16);
    __syncthreads();

    bf16x8 qa[2];
    #pragma unroll
    for (int kk = 0; kk < 2; ++kk){
      int row = w*16 + l15;
      qa[kk] = *(const bf16x8*)((const char*)Qs + row*128 + ((lg*16 + kk*64) ^ ((row & 7) << 4)));
    }
    float e[4][4];
    #pragma unroll
    for (int nb = 0; nb < 4; ++nb){
      f32x4 s = fz;
      #pragma unroll
      for (int kk = 0; kk < 2; ++kk){
        int row = nb*16 + l15;
        bf16x8 kb = *(const bf16x8*)((const char*)Ks + row*128 + ((lg*16 + kk*64) ^ ((row & 7) << 4)));
        s = __builtin_amdgcn_mfma_f32_16x16x32_bf16(qa[kk], kb, s, 0, 0, 0);
      }
      #pragma unroll
      for (int r = 0; r < 4; ++r) e[nb][r] = __expf(s[r] * 0.125f);
    }
    #pragma unroll
    for (int nb = 0; nb < 4; ++nb){
      float cp = e[nb][0] + e[nb][1] + e[nb][2] + e[nb][3];
      cp += __shfl_xor(cp, 16);
      cp += __shfl_xor(cp, 32);
      if (lg == 0) red[w*64 + nb*16 + l15] = cp;
    }
    __syncthreads();

    #pragma unroll
    for (int nb = 0; nb < 4; ++nb){
      int col = nb*16 + l15;
      float dn = red[col] + red[64 + col] + red[128 + col] + red[192 + col];
      float inv = 1.0f / dn;
      #pragma unroll
      for (int r = 0; r < 4; ++r){
        int row = w*16 + lg*4 + r;
        Al[row*64 + ((((2*col)) ^ ((row & 7) << 4)) >> 1)] = f2bf(e[nb][r] * inv);
      }
    }
    #pragma unroll
    for (int ee = 0; ee < 8; ++ee){
      int c0 = vcg*16 + ee;
      int sw0 = (((c0 & 7) ^ (c0 >> 3)) & 7) << 4;
      Vt[c0*64 + (((2*vtok) ^ sw0) >> 1)] = v0[ee];
    }
    #pragma unroll
    for (int ee = 0; ee < 8; ++ee){
      int c1 = vcg*16 + 8 + ee;
      int sw1 = (((c1 & 7) ^ (c1 >> 3)) & 7) << 4;
      Vt[c1*64 + (((2*vtok) ^ sw1) >> 1)] = v1[ee];
    }
    __syncthreads();

    bf16x8 aa[2];
    #pragma unroll
    for (int kk = 0; kk < 2; ++kk){
      int row = w*16 + l15;
      aa[kk] = *(const bf16x8*)((const char*)Al + row*128 + ((lg*16 + kk*64) ^ ((row & 7) << 4)));
    }
    #pragma unroll
    for (int nb = 0; nb < 5; ++nb){
      #pragma unroll
      for (int kk = 0; kk < 2; ++kk){
        int row = nb*16 + l15;
        int sw = (((row & 7) ^ (row >> 3)) & 7) << 4;
        bf16x8 vb = *(const bf16x8*)((const char*)Vt + row*128 + ((lg*16 + kk*64) ^ sw));
        acc[nb] = __builtin_amdgcn_mfma_f32_16x16x32_bf16(aa[kk], vb, acc[nb], 0, 0, 0);
      }
    }
  }

  float* Pb = P + (size_t)(bh*NCHUNK + chunk) * 64 * 80;
  #pragma unroll
  for (int nb = 0; nb < 5; ++nb){
    #pragma unroll
    for (int r = 0; r < 4; ++r){
      int s = w*16 + lg*4 + r;
      Pb[(size_t)s*80 + nb*16 + l15] = acc[nb][r];
    }
  }
}

__global__ void reduce_out(const float* __restrict__ P, float* __restrict__ out){
  int flat = blockIdx.x * 256 + threadIdx.x;
  int c = flat & 63, s = (flat >> 6) & 63, bh = flat >> 12;
  int bb = bh >> 4, h = bh & 15;
  float sc = 0.f, sn = 0.f;
  #pragma unroll
  for (int ch = 0; ch < NCHUNK; ++ch){
    const float* base = P + ((size_t)(bh*NCHUNK + ch)*64 + s)*80;
    sc += base[c];
    sn += base[64];
  }
  out[((size_t)s*BATCH + bb)*1024 + h*64 + c] = sc / (sn + 0.001f);
}

extern "C" void kernel_launch(void* const* d_in, const int* in_sizes, int n_in,
                              void* d_out, int out_size, void* d_ws, size_t ws_size,
                              hipStream_t stream)
{
  const float* s  = (const float*)d_in[0];
  const float* d  = (const float*)d_in[1];
  const float* Wq = (const float*)d_in[2];
  const float* bq = (const float*)d_in[3];
  const float* Wk = (const float*)d_in[4];
  const float* bk = (const float*)d_in[5];
  const float* Wv = (const float*)d_in[6];
  const float* bv = (const float*)d_in[7];
  float* out = (float*)d_out;

  char* ws = (char*)d_ws;
  unsigned short* dbf = (unsigned short*)(ws);               // 67,108,864
  unsigned short* sbf = (unsigned short*)(ws + 67108864);    //  1,048,576
  unsigned short* wqb = (unsigned short*)(ws + 68157440);    //  2,097,152
  unsigned short* wkb = (unsigned short*)(ws + 70254592);    //  2,097,152 (Wk rows 0..1023)
  unsigned short* wvb = (unsigned short*)(ws + 72351744);    //  2,097,152 (Wv rows = wkb rows 1024..2047)
  unsigned short* Qw  = (unsigned short*)(ws + 74448896);    //  1,048,576
  unsigned short* Kw  = (unsigned short*)(ws + 75497472);    // 67,108,864
  unsigned short* Vw  = (unsigned short*)(ws + 142606336);   // 67,108,864
  float*          Pw  = (float*)(ws + 209715200);            // 20,971,520

  (void)in_sizes; (void)n_in; (void)out_size; (void)ws_size;

  cvt_bf16<<<(MD*HC/4 + 255)/256, 256, 0, stream>>>(d,  dbf, MD*HC/4);
  cvt_bf16<<<(MS*HC/4 + 255)/256, 256, 0, stream>>>(s,  sbf, MS*HC/4);
  cvt_bf16<<<(HC*HC/4 + 255)/256, 256, 0, stream>>>(Wq, wqb, HC*HC/4);
  cvt_bf16<<<(HC*HC/4 + 255)/256, 256, 0, stream>>>(Wk, wkb, HC*HC/4);
  cvt_bf16<<<(HC*HC/4 + 255)/256, 256, 0, stream>>>(Wv, wvb, HC*HC/4);

  gemm128<<<(MS/128)*8, 256, 0, stream>>>(sbf, wqb, bq, Qw);
  gemm_kv<<<(MD/256)*8, 512, 0, stream>>>(dbf, wkb, bk, bv, Kw, Vw);

  attn_kernel<<<dim3(128, NCHUNK), 256, 0, stream>>>(Qw, Kw, Vw, Pw);

  reduce_out<<<(TS*BATCH*HC)/256, 256, 0, stream>>>(Pw, out);
}

// Round 5
// 241.231 us; speedup vs baseline: 1.1380x; 1.1380x over previous
//
#include <hip/hip_runtime.h>

// SlotAttention on MI355X (gfx950).
// R4: gemm_kv rebuilt on the m201 8-phase template: 256x256 tile, BK=64,
// 2 K-tile LDS buffers (128 KiB), 8 phases per 2 K-tiles, 2 staging
// global_load_lds per phase (granule schedule proven WAR/RAW-safe by phase
// barriers + counted vmcnt(8/10/6) at phases 3/5/7). Converts fused into one
// kernel. Q GEMM (gemm128) and attention unchanged.

#define TS 64
#define TD 4096
#define BATCH 8
#define HC 1024
#define NHEAD 16
#define MD (TD*BATCH)   // 32768
#define MS (TS*BATCH)   // 512
#define NCHUNK 8
#define CHTOK (TD/NCHUNK) // 512

typedef __attribute__((ext_vector_type(8))) __bf16 bf16x8;
typedef __attribute__((ext_vector_type(4))) float f32x4;
typedef __attribute__((ext_vector_type(4))) unsigned short u16x4;
typedef __attribute__((ext_vector_type(8))) unsigned short u16x8;

__device__ __forceinline__ unsigned short f2bf(float x){
  union { float f; unsigned u; } v; v.f = x;
  unsigned r = v.u + 0x7FFFu + ((v.u >> 16) & 1u);
  return (unsigned short)(r >> 16);
}

__device__ __forceinline__ void gll16(const void* g, void* l){
  __builtin_amdgcn_global_load_lds((__attribute__((address_space(1))) void*)g,
                                   (__attribute__((address_space(3))) void*)l, 16, 0, 0);
}

// Fused f32->bf16 convert for all five inputs (one launch).
// f32x4 units: d 8388608 | s 131072 | Wq 262144 | Wk 262144 | Wv 262144.
__global__ void cvt_all(const float* __restrict__ d, const float* __restrict__ s,
                        const float* __restrict__ wq, const float* __restrict__ wk,
                        const float* __restrict__ wv,
                        unsigned short* __restrict__ dbf, unsigned short* __restrict__ sbf,
                        unsigned short* __restrict__ wqb, unsigned short* __restrict__ wkb,
                        unsigned short* __restrict__ wvb){
  long i = (long)blockIdx.x * 256 + threadIdx.x;
  const float* src; unsigned short* dst; long off;
  if (i < 8388608L)      { src = d;  dst = dbf; off = i; }
  else if (i < 8519680L) { src = s;  dst = sbf; off = i - 8388608L; }
  else if (i < 8781824L) { src = wq; dst = wqb; off = i - 8519680L; }
  else if (i < 9043968L) { src = wk; dst = wkb; off = i - 8781824L; }
  else                   { src = wv; dst = wvb; off = i - 9043968L; }
  f32x4 f = ((const f32x4*)src)[off];
  u16x4 o;
  o[0] = f2bf(f[0]); o[1] = f2bf(f[1]); o[2] = f2bf(f[2]); o[3] = f2bf(f[3]);
  ((u16x4*)dst)[off] = o;
}

// ---------------------------------------------------------------------------
// Fused K|V GEMM: C[32768 x 2048] = A @ [Wk;Wv]^T + [bk;bv], bf16 in/out.
// m201-style 8-phase schedule. 8 waves (2M x 4N), per-wave output 128x64.
// K-tile = BK=64; buffer buf = kt&1 holds one K-tile (A 32KB + B 32KB).
// Iteration i processes kt=2i (phases P0-3, quadrants 0-3) and kt=2i+1
// (P4-7). Each phase: {ds_reads for this quadrant | 2 staging gll16 |
// [lgkmcnt(8) on 12-read phases] | barrier | lgkmcnt(0)+sched_barrier |
// setprio(1) 16 MFMA setprio(0) | [counted vmcnt at P3/P5/P7] | barrier}.
// Staging granule = 64 rows x 64k (8KB; 1 gll16/wave). Granule placement is
// read-sealed: a granule is staged only in a phase after the phase whose
// barrier sealed all reads of those LDS rows. RAW is enforced by
// vmcnt(8)@P3, vmcnt(10)@P5, vmcnt(6)@P7 (2 loads/wave/phase in flight).
// ---------------------------------------------------------------------------
__global__ __launch_bounds__(512, 2) void gemm_kv(
    const unsigned short* __restrict__ A,     // [32768][1024]
    const unsigned short* __restrict__ W,     // [2048][1024] = Wk rows then Wv rows
    const float* __restrict__ bk,
    const float* __restrict__ bv,
    unsigned short* __restrict__ Kout,
    unsigned short* __restrict__ Vout)
{
  __shared__ unsigned short As[2][256*64];    // 32 KB per buf
  __shared__ unsigned short Bs[2][256*64];

  const int nwg = gridDim.x;                 // 1024
  const int cpx = nwg >> 3;
  const int orig = blockIdx.x;
  const int wg = (orig & 7) * cpx + (orig >> 3);   // bijective XCD swizzle
  const int mt = wg >> 3, nt = wg & 7;
  const int tid = threadIdx.x;
  const int lane = tid & 63, w = tid >> 6;   // 8 waves
  const int l15 = lane & 15, lg = lane >> 4;
  const int wm = w >> 2, wn = w & 3;

  // staging constants: granule g = rows [64g, 64g+64); wave w covers 8 rows.
  const int lr8 = lane >> 3;                         // 0..7
  const unsigned sch8 = (unsigned)((lane & 7) ^ lr8) << 4;  // pre-swizzled chunk
  const char* aBase = (const char*)A + (size_t)mt * 256 * 2048;
  const char* bBase = (const char*)W + (size_t)nt * 256 * 2048;
  unsigned rowbyte[4]; unsigned ldsg[4];
  #pragma unroll
  for (int g = 0; g < 4; ++g){
    rowbyte[g] = (unsigned)((g*64 + w*8 + lr8) * 2048) + sch8;
    ldsg[g]    = (unsigned)((g*64 + w*8) * 128);     // wave-uniform LDS dest
  }

  #define SA(kt_, g_, buf_) { if ((kt_) < 16) gll16(aBase + rowbyte[g_] + (size_t)(kt_)*128, (char*)&As[buf_][0] + ldsg[g_]); }
  #define SB(kt_, g_, buf_) { if ((kt_) < 16) gll16(bBase + rowbyte[g_] + (size_t)(kt_)*128, (char*)&Bs[buf_][0] + ldsg[g_]); }

  // fragment read constants (row&7 == l15&7 since bases are multiples of 8)
  const unsigned arow = (unsigned)(wm*128 + l15) * 128;
  const unsigned brow = (unsigned)(wn*64  + l15) * 128;
  const unsigned ck0 = (unsigned)((lg      ^ (l15 & 7)) << 4);
  const unsigned ck1 = (unsigned)(((4+lg)  ^ (l15 & 7)) << 4);

  #define RD_A(buf_, mf_, kk_) (*(const bf16x8*)((const char*)&As[buf_][0] + arow + (mf_)*2048u + ((kk_) ? ck1 : ck0)))
  #define RD_B(buf_, nf_, kk_) (*(const bf16x8*)((const char*)&Bs[buf_][0] + brow + (nf_)*2048u + ((kk_) ? ck1 : ck0)))

  const f32x4 fz = {0.f, 0.f, 0.f, 0.f};
  f32x4 acc[8][4];
  #pragma unroll
  for (int m = 0; m < 8; ++m)
    #pragma unroll
    for (int n = 0; n < 4; ++n) acc[m][n] = fz;

  #define MMQ(q_) { \
    __builtin_amdgcn_s_setprio(1); \
    _Pragma("unroll") \
    for (int kk = 0; kk < 2; ++kk){ \
      _Pragma("unroll") \
      for (int nf = 0; nf < 4; ++nf){ \
        acc[2*(q_)  ][nf] = __builtin_amdgcn_mfma_f32_16x16x32_bf16(af[0][kk], bfr[nf][kk], acc[2*(q_)  ][nf], 0,0,0); \
        acc[2*(q_)+1][nf] = __builtin_amdgcn_mfma_f32_16x16x32_bf16(af[1][kk], bfr[nf][kk], acc[2*(q_)+1][nf], 0,0,0); \
      } } \
    __builtin_amdgcn_s_setprio(0); }

  #define BAR       { __builtin_amdgcn_s_barrier(); __builtin_amdgcn_sched_barrier(0); }
  #define LGKM0     { asm volatile("s_waitcnt lgkmcnt(0)" ::: "memory"); __builtin_amdgcn_sched_barrier(0); }
  #define LGKM8     { asm volatile("s_waitcnt lgkmcnt(8)" ::: "memory"); __builtin_amdgcn_sched_barrier(0); }

  // ---- prologue: stage kt0 fully, kt1 all-but-A(1)g1,g3 (P0 of iter 0 does those)
  SA(0,0,0) SA(0,1,0) SA(0,2,0) SA(0,3,0)
  SB(0,0,0) SB(0,1,0) SB(0,2,0) SB(0,3,0)
  SB(1,0,1) SB(1,1,1) SB(1,2,1) SB(1,3,1)
  SA(1,0,1) SA(1,2,1)
  asm volatile("s_waitcnt vmcnt(6)" ::: "memory");
  __builtin_amdgcn_sched_barrier(0);
  BAR

  #pragma unroll 1
  for (int i = 0; i < 8; ++i){
    const int kodd = 2*i + 1, s2 = 2*i + 2, s3 = 2*i + 3;
    bf16x8 bfr[4][2];

    { // ---- P0: kt quadrant 0 (12 reads) | stage A(kodd) g1,g3 -> buf1
      bf16x8 af[2][2];
      #pragma unroll
      for (int nf = 0; nf < 4; ++nf){ bfr[nf][0] = RD_B(0, nf, 0); bfr[nf][1] = RD_B(0, nf, 1); }
      af[0][0] = RD_A(0, 0, 0); af[0][1] = RD_A(0, 0, 1);
      af[1][0] = RD_A(0, 1, 0); af[1][1] = RD_A(0, 1, 1);
      SA(kodd, 1, 1) SA(kodd, 3, 1)
      LGKM8
      BAR
      LGKM0
      MMQ(0)
      BAR
    }
    { // ---- P1: q1 | stage B(s2) g0,g1 -> buf0
      bf16x8 af[2][2];
      af[0][0] = RD_A(0, 2, 0); af[0][1] = RD_A(0, 2, 1);
      af[1][0] = RD_A(0, 3, 0); af[1][1] = RD_A(0, 3, 1);
      SB(s2, 0, 0) SB(s2, 1, 0)
      BAR
      LGKM0
      MMQ(1)
      BAR
    }
    { // ---- P2: q2 | stage A(s2) g0,g2 -> buf0
      bf16x8 af[2][2];
      af[0][0] = RD_A(0, 4, 0); af[0][1] = RD_A(0, 4, 1);
      af[1][0] = RD_A(0, 5, 0); af[1][1] = RD_A(0, 5, 1);
      SA(s2, 0, 0) SA(s2, 2, 0)
      BAR
      LGKM0
      MMQ(2)
      BAR
    }
    { // ---- P3: q3 | stage B(s2) g2,g3 | boundary vmcnt(8)
      bf16x8 af[2][2];
      af[0][0] = RD_A(0, 6, 0); af[0][1] = RD_A(0, 6, 1);
      af[1][0] = RD_A(0, 7, 0); af[1][1] = RD_A(0, 7, 1);
      SB(s2, 2, 0) SB(s2, 3, 0)
      BAR
      LGKM0
      MMQ(3)
      __builtin_amdgcn_sched_barrier(0);
      if (i < 7) { asm volatile("s_waitcnt vmcnt(8)" ::: "memory"); }
      else       { asm volatile("s_waitcnt vmcnt(2)" ::: "memory"); }
      __builtin_amdgcn_sched_barrier(0);
      BAR
    }
    { // ---- P4: kt+1 quadrant 0 (12 reads) | stage A(s2) g1,g3 -> buf0
      bf16x8 af[2][2];
      #pragma unroll
      for (int nf = 0; nf < 4; ++nf){ bfr[nf][0] = RD_B(1, nf, 0); bfr[nf][1] = RD_B(1, nf, 1); }
      af[0][0] = RD_A(1, 0, 0); af[0][1] = RD_A(1, 0, 1);
      af[1][0] = RD_A(1, 1, 0); af[1][1] = RD_A(1, 1, 1);
      SA(s2, 1, 0) SA(s2, 3, 0)
      LGKM8
      BAR
      LGKM0
      MMQ(0)
      BAR
    }
    { // ---- P5: q1 | stage B(s3) g0,g1 -> buf1 | boundary vmcnt(10)
      bf16x8 af[2][2];
      af[0][0] = RD_A(1, 2, 0); af[0][1] = RD_A(1, 2, 1);
      af[1][0] = RD_A(1, 3, 0); af[1][1] = RD_A(1, 3, 1);
      SB(s3, 0, 1) SB(s3, 1, 1)
      BAR
      LGKM0
      MMQ(1)
      __builtin_amdgcn_sched_barrier(0);
      if (i < 7) { asm volatile("s_waitcnt vmcnt(10)" ::: "memory"); }
      else       { asm volatile("s_waitcnt vmcnt(0)" ::: "memory"); }
      __builtin_amdgcn_sched_barrier(0);
      BAR
    }
    { // ---- P6: q2 | stage A(s3) g0,g2 -> buf1
      bf16x8 af[2][2];
      af[0][0] = RD_A(1, 4, 0); af[0][1] = RD_A(1, 4, 1);
      af[1][0] = RD_A(1, 5, 0); af[1][1] = RD_A(1, 5, 1);
      SA(s3, 0, 1) SA(s3, 2, 1)
      BAR
      LGKM0
      MMQ(2)
      BAR
    }
    { // ---- P7: q3 | stage B(s3) g2,g3 | boundary vmcnt(6)
      bf16x8 af[2][2];
      af[0][0] = RD_A(1, 6, 0); af[0][1] = RD_A(1, 6, 1);
      af[1][0] = RD_A(1, 7, 0); af[1][1] = RD_A(1, 7, 1);
      SB(s3, 2, 1) SB(s3, 3, 1)
      BAR
      LGKM0
      MMQ(3)
      __builtin_amdgcn_sched_barrier(0);
      if (i < 7) { asm volatile("s_waitcnt vmcnt(6)" ::: "memory"); }
      __builtin_amdgcn_sched_barrier(0);
      BAR
    }
  }

  // ---- epilogue: bias + bf16 store (block's 256 cols uniformly K or V)
  const int ccol = (nt & 3)*256 + wn*64;
  unsigned short* Cb = (nt < 4) ? Kout : Vout;
  const float* bias = (nt < 4) ? bk : bv;
  float bvv[4];
  #pragma unroll
  for (int nf = 0; nf < 4; ++nf) bvv[nf] = bias[ccol + nf*16 + l15];
  #pragma unroll
  for (int mf = 0; mf < 8; ++mf){
    #pragma unroll
    for (int r = 0; r < 4; ++r){
      size_t row = (size_t)(mt*256 + wm*128 + mf*16 + lg*4 + r);
      unsigned short* cp = Cb + row*1024 + ccol;
      #pragma unroll
      for (int nf = 0; nf < 4; ++nf)
        cp[nf*16 + l15] = f2bf(acc[mf][nf][r] + bvv[nf]);
    }
  }
  #undef SA
  #undef SB
  #undef RD_A
  #undef RD_B
  #undef MMQ
  #undef BAR
  #undef LGKM0
  #undef LGKM8
}

// ---------------------------------------------------------------------------
// 128^2 GEMM kept for Q (M=512): verified in R0.
// ---------------------------------------------------------------------------
__global__ __launch_bounds__(256) void gemm128(
    const unsigned short* __restrict__ A,
    const unsigned short* __restrict__ W,
    const float* __restrict__ bias,
    unsigned short* __restrict__ C)
{
  __shared__ unsigned short As[128*64];
  __shared__ unsigned short Bs[128*64];
  const int nwg = gridDim.x;
  const int cpx = nwg >> 3;
  const int orig = blockIdx.x;
  const int wg = (orig & 7) * cpx + (orig >> 3);
  const int mt = wg >> 3, nt = wg & 7;
  const int tid = threadIdx.x;
  const int lane = tid & 63, w = tid >> 6;
  const int l15 = lane & 15, lg = lane >> 4;
  const int wr = w >> 1, wc = w & 1;

  const int lrow = lane >> 3;
  const int lch  = (lane & 7) << 4;
  const char* pA[4]; const char* pB[4]; unsigned ldsoff[4];
  #pragma unroll
  for (int j = 0; j < 4; ++j){
    int row = w*32 + j*8 + lrow;
    int sw  = lch ^ ((row & 7) << 4);
    pA[j] = (const char*)A + (size_t)(mt*128 + row) * 2048 + sw;
    pB[j] = (const char*)W + (size_t)(nt*128 + row) * 2048 + sw;
    ldsoff[j] = (unsigned)(w*32 + j*8) * 128;
  }

  const f32x4 fz = {0.f, 0.f, 0.f, 0.f};
  f32x4 acc[4][4];
  #pragma unroll
  for (int m = 0; m < 4; ++m)
    #pragma unroll
    for (int n = 0; n < 4; ++n) acc[m][n] = fz;

  for (int kt = 0; kt < 16; ++kt){
    __syncthreads();
    #pragma unroll
    for (int j = 0; j < 4; ++j){
      gll16(pA[j] + (size_t)kt*128, (char*)As + ldsoff[j]);
      gll16(pB[j] + (size_t)kt*128, (char*)Bs + ldsoff[j]);
    }
    __syncthreads();
    #pragma unroll
    for (int kk = 0; kk < 2; ++kk){
      bf16x8 af[4], bfr[4];
      #pragma unroll
      for (int m = 0; m < 4; ++m){
        int row = wr*64 + m*16 + l15;
        af[m] = *(const bf16x8*)((const char*)As + row*128 + ((lg*16 + kk*64) ^ ((row & 7) << 4)));
      }
      #pragma unroll
      for (int n = 0; n < 4; ++n){
        int row = wc*64 + n*16 + l15;
        bfr[n] = *(const bf16x8*)((const char*)Bs + row*128 + ((lg*16 + kk*64) ^ ((row & 7) << 4)));
      }
      #pragma unroll
      for (int m = 0; m < 4; ++m)
        #pragma unroll
        for (int n = 0; n < 4; ++n)
          acc[m][n] = __builtin_amdgcn_mfma_f32_16x16x32_bf16(af[m], bfr[n], acc[m][n], 0, 0, 0);
    }
  }

  const int ccol0 = nt*128 + wc*64;
  float bv[4];
  #pragma unroll
  for (int n = 0; n < 4; ++n) bv[n] = bias[ccol0 + n*16 + l15];
  #pragma unroll
  for (int m = 0; m < 4; ++m){
    #pragma unroll
    for (int r = 0; r < 4; ++r){
      size_t row = (size_t)(mt*128 + wr*64 + m*16 + lg*4 + r);
      unsigned short* cp = C + row*1024 + ccol0;
      #pragma unroll
      for (int n = 0; n < 4; ++n)
        cp[n*16 + l15] = f2bf(acc[m][n][r] + bv[n]);
    }
  }
}

// one block per (b*16+h, chunk). 256 threads = 4 waves; wave w owns slots [16w,16w+16).
__global__ __launch_bounds__(256) void attn_kernel(
    const unsigned short* __restrict__ Q,
    const unsigned short* __restrict__ K,
    const unsigned short* __restrict__ V,
    float* __restrict__ P)
{
  __shared__ unsigned short Qs[64*64];
  __shared__ unsigned short Ks[64*64];
  __shared__ unsigned short Vt[80*64];
  __shared__ unsigned short Al[64*64];
  __shared__ float red[256];

  const int bh = blockIdx.x;
  const int chunk = blockIdx.y;
  const int bb = bh >> 4, h = bh & 15;
  const int tid = threadIdx.x;
  const int lane = tid & 63, w = tid >> 6;
  const int l15 = lane & 15, lg = lane >> 4;
  const int lrow = lane >> 3, lch = (lane & 7) << 4;

  for (int i = tid; i < 16*64; i += 256){
    int r = i >> 6;
    Vt[(64 + r)*64 + (i & 63)] = (r == 0) ? (unsigned short)0x3F80 : (unsigned short)0;
  }

  #pragma unroll
  for (int j = 0; j < 2; ++j){
    int row = w*16 + j*8 + lrow;
    int sw = lch ^ ((row & 7) << 4);
    const char* g = (const char*)Q + (size_t)(row*BATCH + bb)*2048 + h*128 + sw;
    gll16(g, (char*)Qs + (w*16 + j*8)*128);
  }

  const f32x4 fz = {0.f, 0.f, 0.f, 0.f};
  f32x4 acc[5];
  #pragma unroll
  for (int nb = 0; nb < 5; ++nb) acc[nb] = fz;

  const int vtok = tid >> 2;
  const int vcg  = tid & 3;
  const int t0 = chunk * CHTOK;

  for (int tt = 0; tt < CHTOK/64; ++tt){
    const int tb = t0 + tt*64;
    #pragma unroll
    for (int j = 0; j < 2; ++j){
      int row = w*16 + j*8 + lrow;
      int sw = lch ^ ((row & 7) << 4);
      const char* g = (const char*)K + (size_t)((size_t)(tb + row)*BATCH + bb)*2048 + h*128 + sw;
      gll16(g, (char*)Ks + (w*16 + j*8)*128);
    }
    const char* vg = (const char*)V + (size_t)((size_t)(tb + vtok)*BATCH + bb)*2048 + h*128 + vcg*32;
    u16x8 v0 = *(const u16x8*)vg;
    u16x8 v1 = *(const u16x8*)(vg + 16);
    __syncthreads();

    bf16x8 qa[2];
    #pragma unroll
    for (int kk = 0; kk < 2; ++kk){
      int row = w*16 + l15;
      qa[kk] = *(const bf16x8*)((const char*)Qs + row*128 + ((lg*16 + kk*64) ^ ((row & 7) << 4)));
    }
    float e[4][4];
    #pragma unroll
    for (int nb = 0; nb < 4; ++nb){
      f32x4 s = fz;
      #pragma unroll
      for (int kk = 0; kk < 2; ++kk){
        int row = nb*16 + l15;
        bf16x8 kb = *(const bf16x8*)((const char*)Ks + row*128 + ((lg*16 + kk*64) ^ ((row & 7) << 4)));
        s = __builtin_amdgcn_mfma_f32_16x16x32_bf16(qa[kk], kb, s, 0, 0, 0);
      }
      #pragma unroll
      for (int r = 0; r < 4; ++r) e[nb][r] = __expf(s[r] * 0.125f);
    }
    #pragma unroll
    for (int nb = 0; nb < 4; ++nb){
      float cp = e[nb][0] + e[nb][1] + e[nb][2] + e[nb][3];
      cp += __shfl_xor(cp, 16);
      cp += __shfl_xor(cp, 32);
      if (lg == 0) red[w*64 + nb*16 + l15] = cp;
    }
    __syncthreads();

    #pragma unroll
    for (int nb = 0; nb < 4; ++nb){
      int col = nb*16 + l15;
      float dn = red[col] + red[64 + col] + red[128 + col] + red[192 + col];
      float inv = 1.0f / dn;
      #pragma unroll
      for (int r = 0; r < 4; ++r){
        int row = w*16 + lg*4 + r;
        Al[row*64 + ((((2*col)) ^ ((row & 7) << 4)) >> 1)] = f2bf(e[nb][r] * inv);
      }
    }
    #pragma unroll
    for (int ee = 0; ee < 8; ++ee){
      int c0 = vcg*16 + ee;
      int sw0 = (((c0 & 7) ^ (c0 >> 3)) & 7) << 4;
      Vt[c0*64 + (((2*vtok) ^ sw0) >> 1)] = v0[ee];
    }
    #pragma unroll
    for (int ee = 0; ee < 8; ++ee){
      int c1 = vcg*16 + 8 + ee;
      int sw1 = (((c1 & 7) ^ (c1 >> 3)) & 7) << 4;
      Vt[c1*64 + (((2*vtok) ^ sw1) >> 1)] = v1[ee];
    }
    __syncthreads();

    bf16x8 aa[2];
    #pragma unroll
    for (int kk = 0; kk < 2; ++kk){
      int row = w*16 + l15;
      aa[kk] = *(const bf16x8*)((const char*)Al + row*128 + ((lg*16 + kk*64) ^ ((row & 7) << 4)));
    }
    #pragma unroll
    for (int nb = 0; nb < 5; ++nb){
      #pragma unroll
      for (int kk = 0; kk < 2; ++kk){
        int row = nb*16 + l15;
        int sw = (((row & 7) ^ (row >> 3)) & 7) << 4;
        bf16x8 vb = *(const bf16x8*)((const char*)Vt + row*128 + ((lg*16 + kk*64) ^ sw));
        acc[nb] = __builtin_amdgcn_mfma_f32_16x16x32_bf16(aa[kk], vb, acc[nb], 0, 0, 0);
      }
    }
  }

  float* Pb = P + (size_t)(bh*NCHUNK + chunk) * 64 * 80;
  #pragma unroll
  for (int nb = 0; nb < 5; ++nb){
    #pragma unroll
    for (int r = 0; r < 4; ++r){
      int s = w*16 + lg*4 + r;
      Pb[(size_t)s*80 + nb*16 + l15] = acc[nb][r];
    }
  }
}

__global__ void reduce_out(const float* __restrict__ P, float* __restrict__ out){
  int flat = blockIdx.x * 256 + threadIdx.x;
  int c = flat & 63, s = (flat >> 6) & 63, bh = flat >> 12;
  int bb = bh >> 4, h = bh & 15;
  float sc = 0.f, sn = 0.f;
  #pragma unroll
  for (int ch = 0; ch < NCHUNK; ++ch){
    const float* base = P + ((size_t)(bh*NCHUNK + ch)*64 + s)*80;
    sc += base[c];
    sn += base[64];
  }
  out[((size_t)s*BATCH + bb)*1024 + h*64 + c] = sc / (sn + 0.001f);
}

extern "C" void kernel_launch(void* const* d_in, const int* in_sizes, int n_in,
                              void* d_out, int out_size, void* d_ws, size_t ws_size,
                              hipStream_t stream)
{
  const float* s  = (const float*)d_in[0];
  const float* d  = (const float*)d_in[1];
  const float* Wq = (const float*)d_in[2];
  const float* bq = (const float*)d_in[3];
  const float* Wk = (const float*)d_in[4];
  const float* bk = (const float*)d_in[5];
  const float* Wv = (const float*)d_in[6];
  const float* bv = (const float*)d_in[7];
  float* out = (float*)d_out;

  char* ws = (char*)d_ws;
  unsigned short* dbf = (unsigned short*)(ws);               // 67,108,864
  unsigned short* sbf = (unsigned short*)(ws + 67108864);    //  1,048,576
  unsigned short* wqb = (unsigned short*)(ws + 68157440);    //  2,097,152
  unsigned short* wkb = (unsigned short*)(ws + 70254592);    //  2,097,152 (Wk rows 0..1023)
  unsigned short* wvb = (unsigned short*)(ws + 72351744);    //  2,097,152 (Wv rows = wkb rows 1024..2047)
  unsigned short* Qw  = (unsigned short*)(ws + 74448896);    //  1,048,576
  unsigned short* Kw  = (unsigned short*)(ws + 75497472);    // 67,108,864
  unsigned short* Vw  = (unsigned short*)(ws + 142606336);   // 67,108,864
  float*          Pw  = (float*)(ws + 209715200);            // 20,971,520

  (void)in_sizes; (void)n_in; (void)out_size; (void)ws_size;

  cvt_all<<<36352, 256, 0, stream>>>(d, s, Wq, Wk, Wv, dbf, sbf, wqb, wkb, wvb);

  gemm128<<<(MS/128)*8, 256, 0, stream>>>(sbf, wqb, bq, Qw);
  gemm_kv<<<(MD/256)*8, 512, 0, stream>>>(dbf, wkb, bk, bv, Kw, Vw);

  attn_kernel<<<dim3(128, NCHUNK), 256, 0, stream>>>(Qw, Kw, Vw, Pw);

  reduce_out<<<(TS*BATCH*HC)/256, 256, 0, stream>>>(Pw, out);
}